// Round 1
// baseline (1196.446 us; speedup 1.0000x reference)
//
#include <hip/hip_runtime.h>

// Edge scatter-add: out[rows[e]] += values[e] * dot(features[e, 0:5], w[0:5])
// E = 16,777,216 edges, N_FEAT = 5, out = 3,000,000 float32.
// Memory-bound: ~470 MB streamed read. 4 edges/thread -> 20 floats = 5 aligned
// float4 loads from features (byte offset 80*t is 16B-aligned).

__global__ __launch_bounds__(256) void edge_scatter4(
    const float4* __restrict__ feat4,   // features viewed as float4; 5 per thread
    const float4* __restrict__ vals4,   // values viewed as float4
    const float*  __restrict__ w,       // a0_weight, 5 floats (uniform -> scalar loads)
    const int4*   __restrict__ rows4,   // rows viewed as int4
    float*        __restrict__ out,
    int quads)                          // E / 4
{
    int t = blockIdx.x * blockDim.x + threadIdx.x;
    if (t >= quads) return;

    const float w0 = w[0], w1 = w[1], w2 = w[2], w3 = w[3], w4 = w[4];

    const float4* f = feat4 + (size_t)t * 5;
    float4 f0 = f[0];
    float4 f1 = f[1];
    float4 f2 = f[2];
    float4 f3 = f[3];
    float4 f4 = f[4];
    float4 v  = vals4[t];
    int4   r  = rows4[t];

    // edge layout in the 20-float window:
    // e0: f0.x f0.y f0.z f0.w f1.x
    // e1: f1.y f1.z f1.w f2.x f2.y
    // e2: f2.z f2.w f3.x f3.y f3.z
    // e3: f3.w f4.x f4.y f4.z f4.w
    float d0 = v.x * (f0.x*w0 + f0.y*w1 + f0.z*w2 + f0.w*w3 + f1.x*w4);
    float d1 = v.y * (f1.y*w0 + f1.z*w1 + f1.w*w2 + f2.x*w3 + f2.y*w4);
    float d2 = v.z * (f2.z*w0 + f2.w*w1 + f3.x*w2 + f3.y*w3 + f3.z*w4);
    float d3 = v.w * (f3.w*w0 + f4.x*w1 + f4.y*w2 + f4.z*w3 + f4.w*w4);

    atomicAdd(&out[r.x], d0);
    atomicAdd(&out[r.y], d1);
    atomicAdd(&out[r.z], d2);
    atomicAdd(&out[r.w], d3);
}

// Tail path for E % 4 != 0 (not hit at E = 16,777,216, kept for safety).
__global__ void edge_scatter_tail(
    const float* __restrict__ features,
    const float* __restrict__ values,
    const float* __restrict__ w,
    const int*   __restrict__ rows,
    float*       __restrict__ out,
    int start, int E)
{
    int e = start + blockIdx.x * blockDim.x + threadIdx.x;
    if (e >= E) return;
    const float* f = features + (size_t)e * 5;
    float d = values[e] * (f[0]*w[0] + f[1]*w[1] + f[2]*w[2] + f[3]*w[3] + f[4]*w[4]);
    atomicAdd(&out[rows[e]], d);
}

extern "C" void kernel_launch(void* const* d_in, const int* in_sizes, int n_in,
                              void* d_out, int out_size, void* d_ws, size_t ws_size,
                              hipStream_t stream) {
    const float* features = (const float*)d_in[0];   // [E,5]
    const float* values   = (const float*)d_in[1];   // [E]
    const float* a0w      = (const float*)d_in[2];   // [1,5]
    const int*   rows     = (const int*)d_in[3];     // [E]
    float*       out      = (float*)d_out;           // [num_nodes]

    const int E = in_sizes[1];
    const int quads = E / 4;
    const int tail  = E - quads * 4;

    // Harness poisons d_out with 0xAA before every timed call — zero it.
    hipMemsetAsync(out, 0, (size_t)out_size * sizeof(float), stream);

    if (quads > 0) {
        dim3 block(256);
        dim3 grid((quads + 255) / 256);
        edge_scatter4<<<grid, block, 0, stream>>>(
            (const float4*)features, (const float4*)values, a0w,
            (const int4*)rows, out, quads);
    }
    if (tail > 0) {
        edge_scatter_tail<<<dim3(1), dim3(64), 0, stream>>>(
            features, values, a0w, rows, out, quads * 4, E);
    }
}